// Round 5
// baseline (721.429 us; speedup 1.0000x reference)
//
#include <hip/hip_runtime.h>
#include <math.h>

#define N_NODES 50000
#define N_EDGES 800000
#define IN_C 16
#define HID_C 16
#define OUT_C 10
#define N_GRAPHS 500
#define EDGE_DIM 3
#define MLP_HID 25
#define BN_EPS 1e-5f

// persistent mega-kernel geometry: 1 block per CU, trivially co-resident
#define GRID 256
#define BLKT 1024
#define GSZ (GRID * BLKT)            // 262144 threads
#define NWAVES (GRID * (BLKT / 64)) // 4096 waves
#define NCHUNK 196                   // ceil(50000/256) scan chunks

typedef __attribute__((ext_vector_type(8))) _Float16 half8;
typedef __attribute__((ext_vector_type(2))) _Float16 half2v;
typedef __attribute__((ext_vector_type(4))) float f32x4;
union U4H8 { uint4 u; half8 h; half2v p[4]; };
union HU { _Float16 h; unsigned short u; };

// device-scope grid barrier (all GRID blocks co-resident; 1 block/CU).
// ctrl[0]=arrival counter, ctrl[1]=generation. memset to 0 pre-launch.
__device__ __forceinline__ void gbar(int* bar, int* gen) {
    __syncthreads();
    if (threadIdx.x == 0) {
        __threadfence();
        int g = __hip_atomic_load(gen, __ATOMIC_RELAXED, __HIP_MEMORY_SCOPE_AGENT);
        int a = __hip_atomic_fetch_add(bar, 1, __ATOMIC_ACQ_REL, __HIP_MEMORY_SCOPE_AGENT);
        if (a == GRID - 1) {
            __hip_atomic_store(bar, 0, __ATOMIC_RELAXED, __HIP_MEMORY_SCOPE_AGENT);
            __hip_atomic_fetch_add(gen, 1, __ATOMIC_RELEASE, __HIP_MEMORY_SCOPE_AGENT);
        } else {
            while (__hip_atomic_load(gen, __ATOMIC_ACQUIRE, __HIP_MEMORY_SCOPE_AGENT) == g) {
                __builtin_amdgcn_s_sleep(1);
            }
        }
        __threadfence();
    }
    __syncthreads();
}

// ---- edge phase (proven R2 body, grid-stride over 64-edge wave-tiles) ----
__device__ __forceinline__ void edge_phase(
    const unsigned short* __restrict__ xh,
    const int* __restrict__ src, const int* __restrict__ dst,
    const int* __restrict__ rank, const int* __restrict__ off,
    const float4* __restrict__ ea4, const float* __restrict__ AC,
    const unsigned int* __restrict__ WF, float* __restrict__ msg_buf,
    uint4* wf_s, int tid)
{
    for (int gi = tid; gi < 832; gi += BLKT)
        wf_s[gi] = ((const uint4*)WF)[gi];
    __syncthreads();

    const int wave = tid >> 6;
    const int lane = tid & 63;
    const int q    = lane >> 4;
    const int el   = lane & 15;
    const int i0   = (q & 1) * 8;
    const bool bsel = (q >> 1) != 0;
    const int gw   = blockIdx.x * (BLKT / 64) + wave;

    for (int v = gw; v < N_EDGES / 64; v += NWAVES) {
        const int E0 = v * 64;
        const int sAll = src[E0 + lane];
        const int dAll = dst[E0 + lane];
        const int rAll = rank[E0 + lane];
        const int pAll = off[dAll] + rAll;

        int   sT[4];
        float a0[4], a1[4], a2[4];
        #pragma unroll
        for (int t = 0; t < 4; ++t) {
            sT[t] = __shfl(sAll, t*16 + el);
            float4 at = ea4[E0 + t*16 + el];
            a0[t] = at.x; a1[t] = at.y; a2[t] = at.z;
        }

        U4H8 xf[4];
        #pragma unroll
        for (int t = 0; t < 4; ++t)
            xf[t].u = *(const uint4*)(const void*)(xh + (size_t)sT[t]*16 + i0);

        f32x4 acc0 = {0.f,0.f,0.f,0.f}, acc1 = {0.f,0.f,0.f,0.f};
        f32x4 acc2 = {0.f,0.f,0.f,0.f}, acc3 = {0.f,0.f,0.f,0.f};
        #pragma unroll 1
        for (int m = 0; m < 13; ++m) {
            const float4 Ae = *(const float4*)(AC + m*8);
            const float4 Ao = *(const float4*)(AC + m*8 + 4);
            const float A0 = bsel ? Ao.x : Ae.x;
            const float A1 = bsel ? Ao.y : Ae.y;
            const float A2 = bsel ? Ao.z : Ae.z;
            const float A3 = bsel ? Ao.w : Ae.w;
            U4H8 w; w.u = wf_s[m*64 + lane];
            #pragma unroll
            for (int t = 0; t < 4; ++t) {
                float h = fmaxf(fmaf(a2[t], A2, fmaf(a1[t], A1,
                                  fmaf(a0[t], A0, A3))), 0.f);
                _Float16 hh = (_Float16)h;
                half2v h2; h2.x = hh; h2.y = hh;
                U4H8 f;
                #pragma unroll
                for (int j = 0; j < 4; ++j) f.p[j] = h2 * xf[t].p[j];
                f32x4 a = (t==0) ? acc0 : (t==1) ? acc1 : (t==2) ? acc2 : acc3;
                a = __builtin_amdgcn_mfma_f32_16x16x32_f16(w.h, f.h, a, 0, 0, 0);
                if (t==0) acc0 = a; else if (t==1) acc1 = a;
                else if (t==2) acc2 = a; else acc3 = a;
            }
        }

        #pragma unroll
        for (int t = 0; t < 4; ++t) {
            int row = __shfl(pAll, t*16 + el);
            f32x4 a = (t==0) ? acc0 : (t==1) ? acc1 : (t==2) ? acc2 : acc3;
            *(f32x4*)(msg_buf + (size_t)row * HID_C + q*4) = a;
        }
    }
}

// ---- node phase (proven R2 4-thr/node body, grid-stride) ----
__device__ __forceinline__ void node_phase(
    const float* __restrict__ xin, const float* __restrict__ msg_buf,
    const int* __restrict__ off, const float* root_s,
    const float* __restrict__ bias,
    float* __restrict__ xout, unsigned int* __restrict__ xh_out, int gt)
{
    for (int t = gt; t < N_NODES * 4; t += GSZ) {
        int n = t >> 2;
        int c0 = (t & 3) * 4;
        int lo = off[n], hi = off[n+1];
        float inv = 1.f / fmaxf((float)(hi - lo), 1.f);

        const f32x4* m4 = (const f32x4*)msg_buf;
        const int qi = t & 3;
        f32x4 s0 = {0.f,0.f,0.f,0.f}, s1 = {0.f,0.f,0.f,0.f};
        int r = lo;
        for (; r + 2 <= hi; r += 2) {
            s0 += m4[(size_t)r*4 + qi];
            s1 += m4[(size_t)(r+1)*4 + qi];
        }
        if (r < hi) s0 += m4[(size_t)r*4 + qi];
        f32x4 s = s0 + s1;

        const float4 bv = *(const float4*)(bias + c0);
        f32x4 acc;
        acc.x = fmaf(s.x, inv, bv.x);
        acc.y = fmaf(s.y, inv, bv.y);
        acc.z = fmaf(s.z, inv, bv.z);
        acc.w = fmaf(s.w, inv, bv.w);

        const float4* x4 = (const float4*)(xin + (size_t)n * IN_C);
        #pragma unroll
        for (int j = 0; j < 4; ++j) {
            float4 xv = x4[j];
            #pragma unroll
            for (int k = 0; k < 4; ++k) {
                float xi = (k==0) ? xv.x : (k==1) ? xv.y : (k==2) ? xv.z : xv.w;
                const float4 rv = *(const float4*)(root_s + (j*4+k)*HID_C + c0);
                acc.x = fmaf(xi, rv.x, acc.x);
                acc.y = fmaf(xi, rv.y, acc.y);
                acc.z = fmaf(xi, rv.z, acc.z);
                acc.w = fmaf(xi, rv.w, acc.w);
            }
        }

        acc.x = acc.x > 0.f ? acc.x : (expf(acc.x) - 1.f);
        acc.y = acc.y > 0.f ? acc.y : (expf(acc.y) - 1.f);
        acc.z = acc.z > 0.f ? acc.z : (expf(acc.z) - 1.f);
        acc.w = acc.w > 0.f ? acc.w : (expf(acc.w) - 1.f);
        *(f32x4*)(xout + (size_t)n * HID_C + c0) = acc;

        if (xh_out) {
            HU h0, h1, h2, h3;
            h0.h = (_Float16)acc.x; h1.h = (_Float16)acc.y;
            h2.h = (_Float16)acc.z; h3.h = (_Float16)acc.w;
            uint2 pk;
            pk.x = (unsigned int)h0.u | ((unsigned int)h1.u << 16);
            pk.y = (unsigned int)h2.u | ((unsigned int)h3.u << 16);
            ((uint2*)xh_out)[n*4 + qi] = pk;
        }
    }
}

// ---- the whole pipeline as one persistent kernel ----
__global__ __launch_bounds__(BLKT) void mega_kernel(
    const float* __restrict__ xin, const int* __restrict__ src,
    const int* __restrict__ dst, const float* __restrict__ eattr,
    const int* __restrict__ batch,
    const float* __restrict__ W1a, const float* __restrict__ b1a,
    const float* __restrict__ g1, const float* __restrict__ bt1,
    const float* __restrict__ m1, const float* __restrict__ v1,
    const float* __restrict__ W1b, const float* __restrict__ b1b,
    const float* __restrict__ root1, const float* __restrict__ bias1,
    const float* __restrict__ W2a, const float* __restrict__ b2a,
    const float* __restrict__ g2, const float* __restrict__ bt2,
    const float* __restrict__ m2, const float* __restrict__ v2,
    const float* __restrict__ W2b, const float* __restrict__ b2b,
    const float* __restrict__ root2, const float* __restrict__ bias2,
    const float* __restrict__ fcW, const float* __restrict__ fcb,
    float* __restrict__ MSG, float* __restrict__ X1, float* __restrict__ X2,
    int* __restrict__ RANK, int* __restrict__ CNT, int* __restrict__ OFF,
    int* __restrict__ GOFF, unsigned int* __restrict__ WF1,
    unsigned int* __restrict__ WF2, float* __restrict__ AC1,
    float* __restrict__ AC2, int* __restrict__ BSUM, int* __restrict__ BPRE,
    float4* __restrict__ EA4, unsigned int* __restrict__ XH0,
    unsigned int* __restrict__ XH1, float* __restrict__ out,
    int* __restrict__ ctrl)
{
    __shared__ uint4 wf_s[832];          // 13312 B
    __shared__ float root_s[IN_C * HID_C];
    __shared__ int   sc[256];

    const int tid  = threadIdx.x;
    const int gt   = blockIdx.x * BLKT + tid;
    const int wave = tid >> 6;
    const int lane = tid & 63;
    const int gw   = blockIdx.x * (BLKT / 64) + wave;
    int* bar = ctrl;
    int* gen = ctrl + 1;

    // ================= P0: setup =================
    // W-pack (1664 threads)
    if (gt < 1664) {
        int t = gt;
        const float *Wb, *bb; unsigned int *WH;
        int tl = t;
        if (t < 832) { Wb = W1b; bb = b1b; WH = WF1; }
        else { tl = t - 832; Wb = W2b; bb = b2b; WH = WF2; }
        int m = tl >> 6;
        int L = tl & 63;
        int q = L >> 4, o = L & 15;
        unsigned int hi[8];
        for (int j = 0; j < 8; ++j) {
            int kp = m*32 + q*8 + j;
            int k = kp >> 4, i = kp & 15;
            float w = (k < 25) ? Wb[k*256 + i*16 + o] : bb[i*16 + o];
            HU cv; cv.h = (_Float16)w;
            hi[j] = cv.u;
        }
        int base = (m*64 + L) * 4;
        for (int d = 0; d < 4; ++d)
            WH[base + d] = hi[2*d] | (hi[2*d+1] << 16);
    }
    // BN fold
    if (gt < 26) {
        int k = gt;
        if (k < 25) {
            float s = g1[k] / sqrtf(v1[k] + BN_EPS);
            AC1[k*4+0] = s * W1a[0*MLP_HID+k];
            AC1[k*4+1] = s * W1a[1*MLP_HID+k];
            AC1[k*4+2] = s * W1a[2*MLP_HID+k];
            AC1[k*4+3] = s * (b1a[k] - m1[k]) + bt1[k];
        } else {
            AC1[100] = 0.f; AC1[101] = 0.f; AC1[102] = 0.f; AC1[103] = 1.f;
        }
    } else if (gt >= 32 && gt < 58) {
        int k = gt - 32;
        if (k < 25) {
            float s = g2[k] / sqrtf(v2[k] + BN_EPS);
            AC2[k*4+0] = s * W2a[0*MLP_HID+k];
            AC2[k*4+1] = s * W2a[1*MLP_HID+k];
            AC2[k*4+2] = s * W2a[2*MLP_HID+k];
            AC2[k*4+3] = s * (b2a[k] - m2[k]) + bt2[k];
        } else {
            AC2[100] = 0.f; AC2[101] = 0.f; AC2[102] = 0.f; AC2[103] = 1.f;
        }
    }
    // goff binary search (batch sorted)
    if (gt <= N_GRAPHS) {
        int g = gt;
        int lo = 0, hi = N_NODES;
        while (lo < hi) {
            int mid = (lo + hi) >> 1;
            if (batch[mid] < g) lo = mid + 1; else hi = mid;
        }
        GOFF[g] = lo;
    }
    // zero CNT (12500 int4)
    {
        int4* c4 = (int4*)CNT;
        const int4 z4 = {0,0,0,0};
        if (gt < 12500) c4[gt] = z4;
    }
    // eattr repack -> EA4 (float4, edge order)
    for (int e = gt; e < N_EDGES; e += GSZ) {
        float4 a;
        a.x = eattr[e*3+0];
        a.y = eattr[e*3+1];
        a.z = eattr[e*3+2];
        a.w = 0.f;
        EA4[e] = a;
    }
    // x -> f16 pairs
    {
        const float2* x2 = (const float2*)xin;
        for (int i = gt; i < 400000; i += GSZ) {
            float2 v = x2[i];
            HU h0; h0.h = (_Float16)v.x;
            HU h1; h1.h = (_Float16)v.y;
            XH0[i] = (unsigned int)h0.u | ((unsigned int)h1.u << 16);
        }
    }
    gbar(bar, gen);

    // ================= P1: rank =================
    for (int e = gt; e < N_EDGES; e += GSZ)
        RANK[e] = atomicAdd(&CNT[dst[e]], 1);
    gbar(bar, gen);

    // ================= P2a: per-chunk reduce =================
    if (gw < NCHUNK) {
        int i4 = gw*64 + lane;
        int s = 0;
        if (i4 < 12500) {
            int4 v = ((const int4*)CNT)[i4];
            s = v.x + v.y + v.z + v.w;
        }
        #pragma unroll
        for (int d = 1; d < 64; d <<= 1) s += __shfl_xor(s, d);
        if (lane == 0) BSUM[gw] = s;
    }
    gbar(bar, gen);

    // ================= P2b: scan chunk sums (block 0) =================
    if (blockIdx.x == 0) {
        if (tid < 256) sc[tid] = (tid < NCHUNK) ? BSUM[tid] : 0;
        __syncthreads();
        for (int d = 1; d < 256; d <<= 1) {
            int u = 0;
            if (tid < 256 && tid >= d) u = sc[tid - d];
            __syncthreads();
            if (tid < 256) sc[tid] += u;
            __syncthreads();
        }
        if (tid < NCHUNK) BPRE[tid] = (tid > 0) ? sc[tid-1] : 0;
        if (tid == 255) OFF[N_NODES] = sc[255];
    }
    gbar(bar, gen);

    // ================= P2c: per-chunk scan -> OFF =================
    if (gw < NCHUNK) {
        int c = gw;
        int i4 = c*64 + lane;
        int4 v = {0,0,0,0};
        if (i4 < 12500) v = ((const int4*)CNT)[i4];
        int p1 = v.x, p2 = p1 + v.y, p3 = p2 + v.z, tot = p3 + v.w;
        int run = tot;
        #pragma unroll
        for (int d = 1; d < 64; d <<= 1) {
            int u = __shfl_up(run, d);
            if (lane >= d) run += u;
        }
        int excl = run - tot + BPRE[c];
        int idx = i4 * 4;
        if (idx < N_NODES)     OFF[idx]   = excl;
        if (idx+1 < N_NODES)   OFF[idx+1] = excl + p1;
        if (idx+2 < N_NODES)   OFF[idx+2] = excl + p2;
        if (idx+3 < N_NODES)   OFF[idx+3] = excl + p3;
    }
    gbar(bar, gen);

    // ================= P3: edge layer 1 =================
    edge_phase((const unsigned short*)XH0, src, dst, RANK, OFF,
               EA4, AC1, WF1, MSG, wf_s, tid);
    gbar(bar, gen);

    // ================= P4: node layer 1 =================
    for (int i = tid; i < 64; i += BLKT)
        ((float4*)root_s)[i] = ((const float4*)root1)[i];
    __syncthreads();
    node_phase(xin, MSG, OFF, root_s, bias1, X1, XH1, gt);
    gbar(bar, gen);

    // ================= P5: edge layer 2 =================
    edge_phase((const unsigned short*)XH1, src, dst, RANK, OFF,
               EA4, AC2, WF2, MSG, wf_s, tid);
    gbar(bar, gen);

    // ================= P6: node layer 2 =================
    for (int i = tid; i < 64; i += BLKT)
        ((float4*)root_s)[i] = ((const float4*)root2)[i];
    __syncthreads();
    node_phase(X1, MSG, OFF, root_s, bias2, X2, (unsigned int*)nullptr, gt);
    gbar(bar, gen);

    // ================= P7: pool + final linear (wave per graph) ========
    if (gw < N_GRAPHS) {
        int g = gw;
        int c = lane & 15, sub = lane >> 4;
        int lo = GOFF[g], hi = GOFF[g+1];
        float s = 0.f;
        for (int n = lo + sub; n < hi; n += 4)
            s += X2[(size_t)n*HID_C + c];
        s += __shfl_xor(s, 16);
        s += __shfl_xor(s, 32);
        float pooled = s / fmaxf((float)(hi - lo), 1.f);
        float acc = 0.f;
        if (lane < OUT_C) acc = fcb[lane];
        #pragma unroll
        for (int i = 0; i < HID_C; ++i) {
            float pi = __shfl(pooled, i);
            if (lane < OUT_C) acc = fmaf(pi, fcW[i*OUT_C + lane], acc);
        }
        if (lane < OUT_C) out[g*OUT_C + lane] = acc;
    }
}

// ---------------- launch ----------------

extern "C" void kernel_launch(void* const* d_in, const int* in_sizes, int n_in,
                              void* d_out, int out_size, void* d_ws, size_t ws_size,
                              hipStream_t stream)
{
    const float* x     = (const float*)d_in[0];
    const int*   ei    = (const int*)d_in[1];
    const float* eattr = (const float*)d_in[2];
    const int*   batch = (const int*)d_in[3];
    const float* W1a   = (const float*)d_in[4];
    const float* b1a   = (const float*)d_in[5];
    const float* g1    = (const float*)d_in[6];
    const float* bt1   = (const float*)d_in[7];
    const float* m1    = (const float*)d_in[8];
    const float* v1    = (const float*)d_in[9];
    const float* W1b   = (const float*)d_in[10];
    const float* b1b   = (const float*)d_in[11];
    const float* root1 = (const float*)d_in[12];
    const float* bias1 = (const float*)d_in[13];
    const float* W2a   = (const float*)d_in[14];
    const float* b2a   = (const float*)d_in[15];
    const float* g2    = (const float*)d_in[16];
    const float* bt2   = (const float*)d_in[17];
    const float* m2    = (const float*)d_in[18];
    const float* v2    = (const float*)d_in[19];
    const float* W2b   = (const float*)d_in[20];
    const float* b2b   = (const float*)d_in[21];
    const float* root2 = (const float*)d_in[22];
    const float* bias2 = (const float*)d_in[23];
    const float* fcW   = (const float*)d_in[24];
    const float* fcb   = (const float*)d_in[25];

    const int* src = ei;
    const int* dst = ei + N_EDGES;

    float* ws   = (float*)d_ws;
    float* MSG  = ws;                                   // 12,800,000 f
    float* X1   = ws + 12800000;                        //    800,000 f
    float* X2   = ws + 13600000;                        //    800,000 f
    int*   RANK = (int*)(ws + 14400000);                //    800,000 i
    int*   CNT  = (int*)(ws + 15200000);                //     50,000 i (16B al.)
    int*   OFF  = (int*)(ws + 15250000);                //     50,001 i (+pad)
    int*   GOFF = (int*)(ws + 15300064);                //        501 i (+pad)
    unsigned int* WF1 = (unsigned int*)(ws + 15300576); //      3,328 u
    unsigned int* WF2 = (unsigned int*)(ws + 15303904); //      3,328 u
    float* AC1  = ws + 15307232;                        //        104 f (+pad)
    float* AC2  = ws + 15307344;                        //        104 f (+pad)
    int*   BSUM = (int*)(ws + 15307456);                //        196 i (+pad)
    int*   BPRE = (int*)(ws + 15307712);                //        196 i (+pad)
    int*   CTRL = (int*)(ws + 15307968);                //          2 i (+pad)
    float* EA4  = ws + 15308032;                        //  3,200,000 f (16B al.)
    unsigned int* XH0 = (unsigned int*)(ws + 18508032); //    400,000 u (f16 x)
    unsigned int* XH1 = (unsigned int*)(ws + 18908032); //    400,000 u (f16 X1)
    // total ~19,308,032 f = 77.2 MB

    hipMemsetAsync(CTRL, 0, 2 * sizeof(int), stream);

    mega_kernel<<<GRID, BLKT, 0, stream>>>(
        x, src, dst, eattr, batch,
        W1a, b1a, g1, bt1, m1, v1, W1b, b1b, root1, bias1,
        W2a, b2a, g2, bt2, m2, v2, W2b, b2b, root2, bias2,
        fcW, fcb,
        MSG, X1, X2, RANK, CNT, OFF, GOFF, WF1, WF2,
        AC1, AC2, BSUM, BPRE, (float4*)EA4, XH0, XH1,
        (float*)d_out, CTRL);
}

// Round 6
// 261.168 us; speedup vs baseline: 2.7623x; 2.7623x over previous
//
#include <hip/hip_runtime.h>
#include <math.h>

#define N_NODES 50000
#define N_EDGES 800000
#define IN_C 16
#define HID_C 16
#define OUT_C 10
#define N_GRAPHS 500
#define EDGE_DIM 3
#define MLP_HID 25
#define BN_EPS 1e-5f

#define SCAN_NB ((N_NODES + 255) / 256)   // 196 blocks
#define NZB 200                           // repack/rank blocks in setup

typedef __attribute__((ext_vector_type(8))) _Float16 half8;
typedef __attribute__((ext_vector_type(2))) _Float16 half2v;
typedef __attribute__((ext_vector_type(4))) float f32x4;
union U4H8 { uint4 u; half8 h; half2v p[4]; };
union HU { _Float16 h; unsigned short u; };

// ---------------- setup: W-pack(f16) + BN-fold + goff + repack + rank -------
// CNT/TICK/FLAG are pre-zeroed by a hipMemsetAsync ordered before this kernel,
// so blocks 9..208 can run the rank atomicAdd phase directly (the old
// standalone rank_kernel dispatch is deleted).
__global__ __launch_bounds__(256) void setup_kernel(
    const float* __restrict__ W1a, const float* __restrict__ b1a,
    const float* __restrict__ g1, const float* __restrict__ bt1,
    const float* __restrict__ m1, const float* __restrict__ v1,
    const float* __restrict__ W2a, const float* __restrict__ b2a,
    const float* __restrict__ g2, const float* __restrict__ bt2,
    const float* __restrict__ m2, const float* __restrict__ v2,
    const float* __restrict__ W1b, const float* __restrict__ b1b,
    const float* __restrict__ W2b, const float* __restrict__ b2b,
    const int* __restrict__ batch,
    const float* __restrict__ xin, const float* __restrict__ eattr,
    const int* __restrict__ dst,
    float* __restrict__ AC1, float* __restrict__ AC2,
    unsigned int* __restrict__ WF1, unsigned int* __restrict__ WF2,
    int* __restrict__ goff, int* __restrict__ cnt, int* __restrict__ rank_out,
    float4* __restrict__ ea4, unsigned int* __restrict__ xh0)
{
    const int blk = blockIdx.x;
    const int tid = threadIdx.x;
    if (blk < 7) {
        int t = blk * 256 + tid;
        if (t >= 1664) return;
        const float *Wb, *bb; unsigned int *WH;
        int tl = t;
        if (t < 832) { Wb = W1b; bb = b1b; WH = WF1; }
        else { tl = t - 832; Wb = W2b; bb = b2b; WH = WF2; }
        int m = tl >> 6;
        int L = tl & 63;
        int q = L >> 4, o = L & 15;
        unsigned int hi[8];
        for (int j = 0; j < 8; ++j) {
            int kp = m*32 + q*8 + j;          // 0..415
            int k = kp >> 4, i = kp & 15;
            float w = (k < 25) ? Wb[k*256 + i*16 + o] : bb[i*16 + o];
            HU cv; cv.h = (_Float16)w;        // f16 RNE
            hi[j] = cv.u;
        }
        int base = (m*64 + L) * 4;
        for (int d = 0; d < 4; ++d)
            WH[base + d] = hi[2*d] | (hi[2*d+1] << 16);
        return;
    }
    if (blk == 7 || blk == 8) {
        if (blk == 7) {
            if (tid < 26) {
                int k = tid;
                if (k < 25) {
                    float sc = g1[k] / sqrtf(v1[k] + BN_EPS);
                    AC1[k*4+0] = sc * W1a[0*MLP_HID+k];
                    AC1[k*4+1] = sc * W1a[1*MLP_HID+k];
                    AC1[k*4+2] = sc * W1a[2*MLP_HID+k];
                    AC1[k*4+3] = sc * (b1a[k] - m1[k]) + bt1[k];
                } else {
                    AC1[100] = 0.f; AC1[101] = 0.f; AC1[102] = 0.f; AC1[103] = 1.f;
                }
            } else if (tid >= 32 && tid < 58) {
                int k = tid - 32;
                if (k < 25) {
                    float sc = g2[k] / sqrtf(v2[k] + BN_EPS);
                    AC2[k*4+0] = sc * W2a[0*MLP_HID+k];
                    AC2[k*4+1] = sc * W2a[1*MLP_HID+k];
                    AC2[k*4+2] = sc * W2a[2*MLP_HID+k];
                    AC2[k*4+3] = sc * (b2a[k] - m2[k]) + bt2[k];
                } else {
                    AC2[100] = 0.f; AC2[101] = 0.f; AC2[102] = 0.f; AC2[103] = 1.f;
                }
            }
        }
        int g = (blk - 7) * 256 + tid;
        if (g <= N_GRAPHS) {
            int lo = 0, hi = N_NODES;
            while (lo < hi) {
                int mid = (lo + hi) >> 1;
                if (batch[mid] < g) lo = mid + 1; else hi = mid;
            }
            goff[g] = lo;
        }
        return;
    }
    // repack + rank phase (CNT pre-zeroed by memset; stream-ordered)
    const int bt = (blk - 9) * 256 + tid;
    const int STR = NZB * 256;                 // 51200
    for (int e = bt; e < N_EDGES; e += STR) {
        float4 a;
        a.x = eattr[e*3+0];
        a.y = eattr[e*3+1];
        a.z = eattr[e*3+2];
        a.w = 0.f;
        ea4[e] = a;
    }
    const float2* x2 = (const float2*)xin;     // 400,000 f32 pairs
    for (int i = bt; i < 400000; i += STR) {
        float2 v = x2[i];
        HU h0; h0.h = (_Float16)v.x;
        HU h1; h1.h = (_Float16)v.y;
        xh0[i] = (unsigned int)h0.u | ((unsigned int)h1.u << 16);
    }
    for (int e = bt; e < N_EDGES; e += STR)
        rank_out[e] = atomicAdd(&cnt[dst[e]], 1);
}

// ---------------- CSR offsets: single-pass scan --------------------------
// Per-block local scan; last-arriving block (proven ticket pattern from the
// old scan_p1) scans the 196 chunk sums and publishes BPRE + a release flag;
// the other 195 blocks (all trivially co-resident: 196 blocks < 256 CUs)
// wait on the flag with RELAXED polls + one fence (NOT the R5 repeated
// acquire pattern), then write their OFF chunk. Merges old scan_p1+scan_p3.
__global__ __launch_bounds__(256) void scan_kernel(
    const int* __restrict__ cnt, int* __restrict__ bsum,
    int* __restrict__ bpre, int* __restrict__ off,
    int* __restrict__ ticket, int* __restrict__ flag)
{
    __shared__ int lds[256];
    __shared__ int sDone;
    int t = threadIdx.x;
    int idx = blockIdx.x * 256 + t;
    int v = (idx < N_NODES) ? cnt[idx] : 0;
    lds[t] = v;
    __syncthreads();
    for (int d = 1; d < 256; d <<= 1) {
        int u = (t >= d) ? lds[t - d] : 0;
        __syncthreads();
        lds[t] += u;
        __syncthreads();
    }
    const int myincl = lds[t];     // inclusive prefix within block
    const int btot   = lds[255];
    if (t == 0) {
        bsum[blockIdx.x] = btot;
        __threadfence();
        sDone = atomicAdd(ticket, 1);
    }
    __syncthreads();
    if (sDone == SCAN_NB - 1) {
        // aggregator: scan chunk sums, publish bpre, release flag
        __threadfence();
        int b = (t < SCAN_NB) ? bsum[t] : 0;
        __syncthreads();
        lds[t] = b;
        __syncthreads();
        for (int d = 1; d < 256; d <<= 1) {
            int u = (t >= d) ? lds[t - d] : 0;
            __syncthreads();
            lds[t] += u;
            __syncthreads();
        }
        if (t < SCAN_NB) bpre[t] = (t > 0) ? lds[t - 1] : 0;
        if (t == 255) off[N_NODES] = lds[255];
        __threadfence();
        if (t == 0)
            __hip_atomic_store(flag, 1, __ATOMIC_RELEASE,
                               __HIP_MEMORY_SCOPE_AGENT);
    } else {
        if (t == 0) {
            while (__hip_atomic_load(flag, __ATOMIC_RELAXED,
                                     __HIP_MEMORY_SCOPE_AGENT) == 0)
                __builtin_amdgcn_s_sleep(2);
            __threadfence();
        }
        __syncthreads();
    }
    if (idx < N_NODES) off[idx] = bpre[blockIdx.x] + myincl - v;
}

// ---------------- hot path: f16 MFMA edge kernel, 4 tiles/wave --------------
// (byte-identical to the R2 251.4us version)
__global__ __launch_bounds__(256) void edge_mfma7_kernel(
    const unsigned short* __restrict__ xh,
    const int* __restrict__ src,
    const int* __restrict__ dst,
    const int* __restrict__ rank,
    const int* __restrict__ off,
    const float4* __restrict__ ea4,
    const float* __restrict__ AC,
    const unsigned int* __restrict__ WF,
    float* __restrict__ msg_buf)
{
    __shared__ uint4 wf_s[832];                         // 13312 B
    const int tid = threadIdx.x;
    #pragma unroll
    for (int it = 0; it < 4; ++it) {
        int gi = tid + it*256;
        if (gi < 832) wf_s[gi] = ((const uint4*)WF)[gi];
    }
    __syncthreads();

    const int wave = tid >> 6;
    const int lane = tid & 63;
    const int q    = lane >> 4;
    const int el   = lane & 15;
    const int i0   = (q & 1) * 8;
    const bool bsel = (q >> 1) != 0;
    const int E0   = (blockIdx.x * 4 + wave) * 64;

    // coalesced scalar plane: lane L <-> edge E0+L
    const int sAll = src[E0 + lane];
    const int dAll = dst[E0 + lane];
    const int rAll = rank[E0 + lane];
    const int pAll = off[dAll] + rAll;     // CSR slot of edge E0+lane

    // per-tile src via shuffle; eattr as one float4 per (t,el)
    int   sT[4];
    float a0[4], a1[4], a2[4];
    #pragma unroll
    for (int t = 0; t < 4; ++t) {
        sT[t] = __shfl(sAll, t*16 + el);
        float4 at = ea4[E0 + t*16 + el];
        a0[t] = at.x; a1[t] = at.y; a2[t] = at.z;
    }

    // x gather: one dwordx4 of pre-converted f16 per tile
    U4H8 xf[4];
    #pragma unroll
    for (int t = 0; t < 4; ++t)
        xf[t].u = *(const uint4*)(const void*)(xh + (size_t)sT[t]*16 + i0);

    f32x4 acc0 = {0.f,0.f,0.f,0.f}, acc1 = {0.f,0.f,0.f,0.f};
    f32x4 acc2 = {0.f,0.f,0.f,0.f}, acc3 = {0.f,0.f,0.f,0.f};
    #pragma unroll 1
    for (int m = 0; m < 13; ++m) {
        // wave-uniform s_load of AC rows 2m, 2m+1; per-lane parity select
        const float4 Ae = *(const float4*)(AC + m*8);
        const float4 Ao = *(const float4*)(AC + m*8 + 4);
        const float A0 = bsel ? Ao.x : Ae.x;
        const float A1 = bsel ? Ao.y : Ae.y;
        const float A2 = bsel ? Ao.z : Ae.z;
        const float A3 = bsel ? Ao.w : Ae.w;
        U4H8 w; w.u = wf_s[m*64 + lane];     // ds_read_b128 (LDS pipe)
        #pragma unroll
        for (int t = 0; t < 4; ++t) {
            float h = fmaxf(fmaf(a2[t], A2, fmaf(a1[t], A1,
                              fmaf(a0[t], A0, A3))), 0.f);
            _Float16 hh = (_Float16)h;
            half2v h2; h2.x = hh; h2.y = hh;
            U4H8 f;
            #pragma unroll
            for (int j = 0; j < 4; ++j) f.p[j] = h2 * xf[t].p[j];
            // swapped operands: D = W'^T @ H^T = msg^T
            f32x4 a = (t==0) ? acc0 : (t==1) ? acc1 : (t==2) ? acc2 : acc3;
            a = __builtin_amdgcn_mfma_f32_16x16x32_f16(w.h, f.h, a, 0, 0, 0);
            if (t==0) acc0 = a; else if (t==1) acc1 = a;
            else if (t==2) acc2 = a; else acc3 = a;
        }
    }

    // lane (q,el) holds msg[edge el][o=q*4..q*4+3] -> one dwordx4 per tile
    #pragma unroll
    for (int t = 0; t < 4; ++t) {
        int row = __shfl(pAll, t*16 + el);
        f32x4 a = (t==0) ? acc0 : (t==1) ? acc1 : (t==2) ? acc2 : acc3;
        *(f32x4*)(msg_buf + (size_t)row * HID_C + q*4) = a;
    }
}

// 4 threads per node (thread = 4-channel group). Segment-sum msg rows
// [off[n], off[n+1]) as f32x4 -> mean -> + x@root (LDS) + bias -> ELU.
// (byte-identical to the R2 251.4us version)
__global__ __launch_bounds__(256) void node_gather_kernel(
    const float* __restrict__ xin, const float* __restrict__ msg_buf,
    const int* __restrict__ off,
    const float* __restrict__ root, const float* __restrict__ bias,
    float* __restrict__ xout, unsigned int* __restrict__ xh_out)
{
    __shared__ float root_s[IN_C * HID_C];
    if (threadIdx.x < 64)
        ((float4*)root_s)[threadIdx.x] = ((const float4*)root)[threadIdx.x];
    __syncthreads();

    int t = blockIdx.x * blockDim.x + threadIdx.x;
    int n = t >> 2;
    if (n >= N_NODES) return;
    int c0 = (t & 3) * 4;
    int lo = off[n], hi = off[n+1];
    float inv = 1.f / fmaxf((float)(hi - lo), 1.f);

    const f32x4* m4 = (const f32x4*)msg_buf;
    const int qi = c0 >> 2;
    f32x4 s0 = {0.f,0.f,0.f,0.f}, s1 = {0.f,0.f,0.f,0.f};
    int r = lo;
    for (; r + 2 <= hi; r += 2) {
        s0 += m4[(size_t)r*4 + qi];
        s1 += m4[(size_t)(r+1)*4 + qi];
    }
    if (r < hi) s0 += m4[(size_t)r*4 + qi];
    f32x4 s = s0 + s1;

    const float4 bv = *(const float4*)(bias + c0);
    f32x4 acc;
    acc.x = fmaf(s.x, inv, bv.x);
    acc.y = fmaf(s.y, inv, bv.y);
    acc.z = fmaf(s.z, inv, bv.z);
    acc.w = fmaf(s.w, inv, bv.w);

    const float4* x4 = (const float4*)(xin + (size_t)n * IN_C);
    #pragma unroll
    for (int j = 0; j < 4; ++j) {
        float4 xv = x4[j];
        #pragma unroll
        for (int k = 0; k < 4; ++k) {
            float xi = (k==0) ? xv.x : (k==1) ? xv.y : (k==2) ? xv.z : xv.w;
            const float4 rv = *(const float4*)(root_s + (j*4+k)*HID_C + c0);
            acc.x = fmaf(xi, rv.x, acc.x);
            acc.y = fmaf(xi, rv.y, acc.y);
            acc.z = fmaf(xi, rv.z, acc.z);
            acc.w = fmaf(xi, rv.w, acc.w);
        }
    }

    acc.x = acc.x > 0.f ? acc.x : (expf(acc.x) - 1.f);
    acc.y = acc.y > 0.f ? acc.y : (expf(acc.y) - 1.f);
    acc.z = acc.z > 0.f ? acc.z : (expf(acc.z) - 1.f);
    acc.w = acc.w > 0.f ? acc.w : (expf(acc.w) - 1.f);
    *(f32x4*)(xout + (size_t)n * HID_C + c0) = acc;

    if (xh_out) {
        HU h0, h1, h2, h3;
        h0.h = (_Float16)acc.x; h1.h = (_Float16)acc.y;
        h2.h = (_Float16)acc.z; h3.h = (_Float16)acc.w;
        uint2 pk;
        pk.x = (unsigned int)h0.u | ((unsigned int)h1.u << 16);
        pk.y = (unsigned int)h2.u | ((unsigned int)h3.u << 16);
        ((uint2*)xh_out)[n*4 + qi] = pk;
    }
}

// fused: global mean pool (batch sorted -> contiguous segments) + final linear
__global__ __launch_bounds__(64) void pool_final_kernel(
    const float* __restrict__ xin, const int* __restrict__ goff,
    const float* __restrict__ fcW, const float* __restrict__ fcb,
    float* __restrict__ out)
{
    __shared__ float part[4][HID_C];
    __shared__ float pooled[HID_C];
    int g = blockIdx.x;
    int t = threadIdx.x;
    int c = t & 15, sub = t >> 4;
    int lo = goff[g], hi = goff[g+1];
    float s = 0.f;
    for (int n = lo + sub; n < hi; n += 4)
        s += xin[(size_t)n*HID_C + c];
    part[sub][c] = s;
    __syncthreads();
    if (t < HID_C) {
        pooled[t] = (part[0][t] + part[1][t] + part[2][t] + part[3][t])
                    / fmaxf((float)(hi - lo), 1.f);
    }
    __syncthreads();
    if (t < OUT_C) {
        float acc = fcb[t];
        #pragma unroll
        for (int i = 0; i < HID_C; ++i)
            acc = fmaf(pooled[i], fcW[i*OUT_C+t], acc);
        out[g*OUT_C + t] = acc;
    }
}

// ---------------- launch ----------------

extern "C" void kernel_launch(void* const* d_in, const int* in_sizes, int n_in,
                              void* d_out, int out_size, void* d_ws, size_t ws_size,
                              hipStream_t stream)
{
    const float* x     = (const float*)d_in[0];
    const int*   ei    = (const int*)d_in[1];
    const float* eattr = (const float*)d_in[2];
    const int*   batch = (const int*)d_in[3];
    const float* W1a   = (const float*)d_in[4];
    const float* b1a   = (const float*)d_in[5];
    const float* g1    = (const float*)d_in[6];
    const float* bt1   = (const float*)d_in[7];
    const float* m1    = (const float*)d_in[8];
    const float* v1    = (const float*)d_in[9];
    const float* W1b   = (const float*)d_in[10];
    const float* b1b   = (const float*)d_in[11];
    const float* root1 = (const float*)d_in[12];
    const float* bias1 = (const float*)d_in[13];
    const float* W2a   = (const float*)d_in[14];
    const float* b2a   = (const float*)d_in[15];
    const float* g2    = (const float*)d_in[16];
    const float* bt2   = (const float*)d_in[17];
    const float* m2    = (const float*)d_in[18];
    const float* v2    = (const float*)d_in[19];
    const float* W2b   = (const float*)d_in[20];
    const float* b2b   = (const float*)d_in[21];
    const float* root2 = (const float*)d_in[22];
    const float* bias2 = (const float*)d_in[23];
    const float* fcW   = (const float*)d_in[24];
    const float* fcb   = (const float*)d_in[25];

    const int* src = ei;
    const int* dst = ei + N_EDGES;

    float* ws   = (float*)d_ws;
    float* MSG  = ws;                                   // 12,800,000 f
    float* X1   = ws + 12800000;                        //    800,000 f
    float* X2   = ws + 13600000;                        //    800,000 f
    int*   RANK = (int*)(ws + 14400000);                //    800,000 i
    int*   CNT  = (int*)(ws + 15200000);                //     50,000 i
    int*   TICK = (int*)(ws + 15250000);                //          1 i } memset
    int*   FLAG = (int*)(ws + 15250004/4*0 + 15250001); //          1 i } w/ CNT
    int*   OFF  = (int*)(ws + 15250016);                //     50,001 i (+pad)
    int*   GOFF = (int*)(ws + 15300064);                //        501 i (+pad)
    unsigned int* WF1 = (unsigned int*)(ws + 15300576); //      3,328 u
    unsigned int* WF2 = (unsigned int*)(ws + 15303904); //      3,328 u
    float* AC1  = ws + 15307232;                        //        104 f (+pad)
    float* AC2  = ws + 15307344;                        //        104 f (+pad)
    int*   BSUM = (int*)(ws + 15307456);                //        196 i (+pad)
    int*   BPRE = (int*)(ws + 15307712);                //        196 i (+pad)
    float* EA4  = ws + 15308032;                        //  3,200,000 f (16B al.)
    unsigned int* XH0 = (unsigned int*)(ws + 18508032); //    400,000 u (f16 x)
    unsigned int* XH1 = (unsigned int*)(ws + 18908032); //    400,000 u (f16 X1)
    // total ~19,308,032 f = 77.2 MB

    // zero CNT + TICK + FLAG in one stream-ordered fill (50,016 ints)
    hipMemsetAsync(CNT, 0, 50016 * sizeof(int), stream);

    setup_kernel<<<9 + NZB, 256, 0, stream>>>(
        W1a, b1a, g1, bt1, m1, v1, W2a, b2a, g2, bt2, m2, v2,
        W1b, b1b, W2b, b2b, batch, x, eattr, dst,
        AC1, AC2, WF1, WF2, GOFF, CNT, RANK, (float4*)EA4, XH0);
    scan_kernel<<<SCAN_NB, 256, 0, stream>>>(CNT, BSUM, BPRE, OFF, TICK, FLAG);

    edge_mfma7_kernel<<<N_EDGES/256, 256, 0, stream>>>(
        (const unsigned short*)XH0, src, dst, RANK, OFF,
        (const float4*)EA4, AC1, WF1, MSG);
    node_gather_kernel<<<(N_NODES*4 + 255)/256, 256, 0, stream>>>(
        x, MSG, OFF, root1, bias1, X1, XH1);

    edge_mfma7_kernel<<<N_EDGES/256, 256, 0, stream>>>(
        (const unsigned short*)XH1, src, dst, RANK, OFF,
        (const float4*)EA4, AC2, WF2, MSG);
    node_gather_kernel<<<(N_NODES*4 + 255)/256, 256, 0, stream>>>(
        X1, MSG, OFF, root2, bias2, X2, (unsigned int*)nullptr);

    pool_final_kernel<<<N_GRAPHS, 64, 0, stream>>>(X2, GOFF, fcW, fcb, (float*)d_out);
}

// Round 7
// 254.733 us; speedup vs baseline: 2.8321x; 1.0253x over previous
//
#include <hip/hip_runtime.h>
#include <math.h>

#define N_NODES 50000
#define N_EDGES 800000
#define IN_C 16
#define HID_C 16
#define OUT_C 10
#define N_GRAPHS 500
#define EDGE_DIM 3
#define MLP_HID 25
#define BN_EPS 1e-5f

#define SCAN_NB ((N_NODES + 255) / 256)   // 196 blocks
#define EDGE_NB ((N_EDGES + 255) / 256)   // 3125 one-edge-per-thread blocks

typedef __attribute__((ext_vector_type(8))) _Float16 half8;
typedef __attribute__((ext_vector_type(2))) _Float16 half2v;
typedef __attribute__((ext_vector_type(4))) float f32x4;
union U4H8 { uint4 u; half8 h; half2v p[4]; };
union HU { _Float16 h; unsigned short u; };

// ---------------- setup: W-pack(f16) + BN-fold + goff + repack + rank -------
// R6 post-mortem: the 200-block grid-stride repack/rank phase was 1 wave/SIMD
// with 16-deep serial loops -> 44.7us, the longest kernel in the pipeline.
// Now blocks 9.. handle exactly ONE edge per thread (full-width, no loops).
// CNT/TICK/FLAG pre-zeroed by the stream-ordered hipMemsetAsync.
__global__ __launch_bounds__(256) void setup_kernel(
    const float* __restrict__ W1a, const float* __restrict__ b1a,
    const float* __restrict__ g1, const float* __restrict__ bt1,
    const float* __restrict__ m1, const float* __restrict__ v1,
    const float* __restrict__ W2a, const float* __restrict__ b2a,
    const float* __restrict__ g2, const float* __restrict__ bt2,
    const float* __restrict__ m2, const float* __restrict__ v2,
    const float* __restrict__ W1b, const float* __restrict__ b1b,
    const float* __restrict__ W2b, const float* __restrict__ b2b,
    const int* __restrict__ batch,
    const float* __restrict__ xin, const float* __restrict__ eattr,
    const int* __restrict__ dst,
    float* __restrict__ AC1, float* __restrict__ AC2,
    unsigned int* __restrict__ WF1, unsigned int* __restrict__ WF2,
    int* __restrict__ goff, int* __restrict__ cnt, int* __restrict__ rank_out,
    float4* __restrict__ ea4, unsigned int* __restrict__ xh0)
{
    const int blk = blockIdx.x;
    const int tid = threadIdx.x;
    if (blk < 7) {
        int t = blk * 256 + tid;
        if (t >= 1664) return;
        const float *Wb, *bb; unsigned int *WH;
        int tl = t;
        if (t < 832) { Wb = W1b; bb = b1b; WH = WF1; }
        else { tl = t - 832; Wb = W2b; bb = b2b; WH = WF2; }
        int m = tl >> 6;
        int L = tl & 63;
        int q = L >> 4, o = L & 15;
        unsigned int hi[8];
        for (int j = 0; j < 8; ++j) {
            int kp = m*32 + q*8 + j;          // 0..415
            int k = kp >> 4, i = kp & 15;
            float w = (k < 25) ? Wb[k*256 + i*16 + o] : bb[i*16 + o];
            HU cv; cv.h = (_Float16)w;        // f16 RNE
            hi[j] = cv.u;
        }
        int base = (m*64 + L) * 4;
        for (int d = 0; d < 4; ++d)
            WH[base + d] = hi[2*d] | (hi[2*d+1] << 16);
        return;
    }
    if (blk == 7 || blk == 8) {
        if (blk == 7) {
            if (tid < 26) {
                int k = tid;
                if (k < 25) {
                    float sc = g1[k] / sqrtf(v1[k] + BN_EPS);
                    AC1[k*4+0] = sc * W1a[0*MLP_HID+k];
                    AC1[k*4+1] = sc * W1a[1*MLP_HID+k];
                    AC1[k*4+2] = sc * W1a[2*MLP_HID+k];
                    AC1[k*4+3] = sc * (b1a[k] - m1[k]) + bt1[k];
                } else {
                    AC1[100] = 0.f; AC1[101] = 0.f; AC1[102] = 0.f; AC1[103] = 1.f;
                }
            } else if (tid >= 32 && tid < 58) {
                int k = tid - 32;
                if (k < 25) {
                    float sc = g2[k] / sqrtf(v2[k] + BN_EPS);
                    AC2[k*4+0] = sc * W2a[0*MLP_HID+k];
                    AC2[k*4+1] = sc * W2a[1*MLP_HID+k];
                    AC2[k*4+2] = sc * W2a[2*MLP_HID+k];
                    AC2[k*4+3] = sc * (b2a[k] - m2[k]) + bt2[k];
                } else {
                    AC2[100] = 0.f; AC2[101] = 0.f; AC2[102] = 0.f; AC2[103] = 1.f;
                }
            }
        }
        int g = (blk - 7) * 256 + tid;
        if (g <= N_GRAPHS) {
            int lo = 0, hi = N_NODES;
            while (lo < hi) {
                int mid = (lo + hi) >> 1;
                if (batch[mid] < g) lo = mid + 1; else hi = mid;
            }
            goff[g] = lo;
        }
        return;
    }
    // one edge per thread: eattr repack + rank atomic (+x convert for half)
    const int e = (blk - 9) * 256 + tid;
    if (e < N_EDGES) {
        float4 a;
        a.x = eattr[e*3+0];
        a.y = eattr[e*3+1];
        a.z = eattr[e*3+2];
        a.w = 0.f;
        ea4[e] = a;
        rank_out[e] = atomicAdd(&cnt[dst[e]], 1);
    }
    if (e < 400000) {
        float2 v = ((const float2*)xin)[e];
        HU h0; h0.h = (_Float16)v.x;
        HU h1; h1.h = (_Float16)v.y;
        xh0[e] = (unsigned int)h0.u | ((unsigned int)h1.u << 16);
    }
}

// ---------------- CSR offsets: single-pass scan --------------------------
// Per-block local scan; last-arriving block (ticket) scans the 196 chunk
// sums and publishes BPRE + a release flag; the other blocks wait with
// relaxed polls + one fence, then write their OFF chunk. (Verified R6.)
__global__ __launch_bounds__(256) void scan_kernel(
    const int* __restrict__ cnt, int* __restrict__ bsum,
    int* __restrict__ bpre, int* __restrict__ off,
    int* __restrict__ ticket, int* __restrict__ flag)
{
    __shared__ int lds[256];
    __shared__ int sDone;
    int t = threadIdx.x;
    int idx = blockIdx.x * 256 + t;
    int v = (idx < N_NODES) ? cnt[idx] : 0;
    lds[t] = v;
    __syncthreads();
    for (int d = 1; d < 256; d <<= 1) {
        int u = (t >= d) ? lds[t - d] : 0;
        __syncthreads();
        lds[t] += u;
        __syncthreads();
    }
    const int myincl = lds[t];     // inclusive prefix within block
    const int btot   = lds[255];
    if (t == 0) {
        bsum[blockIdx.x] = btot;
        __threadfence();
        sDone = atomicAdd(ticket, 1);
    }
    __syncthreads();
    if (sDone == SCAN_NB - 1) {
        __threadfence();
        int b = (t < SCAN_NB) ? bsum[t] : 0;
        __syncthreads();
        lds[t] = b;
        __syncthreads();
        for (int d = 1; d < 256; d <<= 1) {
            int u = (t >= d) ? lds[t - d] : 0;
            __syncthreads();
            lds[t] += u;
            __syncthreads();
        }
        if (t < SCAN_NB) bpre[t] = (t > 0) ? lds[t - 1] : 0;
        if (t == 255) off[N_NODES] = lds[255];
        __threadfence();
        if (t == 0)
            __hip_atomic_store(flag, 1, __ATOMIC_RELEASE,
                               __HIP_MEMORY_SCOPE_AGENT);
    } else {
        if (t == 0) {
            while (__hip_atomic_load(flag, __ATOMIC_RELAXED,
                                     __HIP_MEMORY_SCOPE_AGENT) == 0)
                __builtin_amdgcn_s_sleep(2);
            __threadfence();
        }
        __syncthreads();
    }
    if (idx < N_NODES) off[idx] = bpre[blockIdx.x] + myincl - v;
}

// ---------------- hot path: f16 MFMA edge kernel, 4 tiles/wave --------------
// (byte-identical to the R2 251.4us version)
__global__ __launch_bounds__(256) void edge_mfma7_kernel(
    const unsigned short* __restrict__ xh,
    const int* __restrict__ src,
    const int* __restrict__ dst,
    const int* __restrict__ rank,
    const int* __restrict__ off,
    const float4* __restrict__ ea4,
    const float* __restrict__ AC,
    const unsigned int* __restrict__ WF,
    float* __restrict__ msg_buf)
{
    __shared__ uint4 wf_s[832];                         // 13312 B
    const int tid = threadIdx.x;
    #pragma unroll
    for (int it = 0; it < 4; ++it) {
        int gi = tid + it*256;
        if (gi < 832) wf_s[gi] = ((const uint4*)WF)[gi];
    }
    __syncthreads();

    const int wave = tid >> 6;
    const int lane = tid & 63;
    const int q    = lane >> 4;
    const int el   = lane & 15;
    const int i0   = (q & 1) * 8;
    const bool bsel = (q >> 1) != 0;
    const int E0   = (blockIdx.x * 4 + wave) * 64;

    // coalesced scalar plane: lane L <-> edge E0+L
    const int sAll = src[E0 + lane];
    const int dAll = dst[E0 + lane];
    const int rAll = rank[E0 + lane];
    const int pAll = off[dAll] + rAll;     // CSR slot of edge E0+lane

    // per-tile src via shuffle; eattr as one float4 per (t,el)
    int   sT[4];
    float a0[4], a1[4], a2[4];
    #pragma unroll
    for (int t = 0; t < 4; ++t) {
        sT[t] = __shfl(sAll, t*16 + el);
        float4 at = ea4[E0 + t*16 + el];
        a0[t] = at.x; a1[t] = at.y; a2[t] = at.z;
    }

    // x gather: one dwordx4 of pre-converted f16 per tile
    U4H8 xf[4];
    #pragma unroll
    for (int t = 0; t < 4; ++t)
        xf[t].u = *(const uint4*)(const void*)(xh + (size_t)sT[t]*16 + i0);

    f32x4 acc0 = {0.f,0.f,0.f,0.f}, acc1 = {0.f,0.f,0.f,0.f};
    f32x4 acc2 = {0.f,0.f,0.f,0.f}, acc3 = {0.f,0.f,0.f,0.f};
    #pragma unroll 1
    for (int m = 0; m < 13; ++m) {
        // wave-uniform s_load of AC rows 2m, 2m+1; per-lane parity select
        const float4 Ae = *(const float4*)(AC + m*8);
        const float4 Ao = *(const float4*)(AC + m*8 + 4);
        const float A0 = bsel ? Ao.x : Ae.x;
        const float A1 = bsel ? Ao.y : Ae.y;
        const float A2 = bsel ? Ao.z : Ae.z;
        const float A3 = bsel ? Ao.w : Ae.w;
        U4H8 w; w.u = wf_s[m*64 + lane];     // ds_read_b128 (LDS pipe)
        #pragma unroll
        for (int t = 0; t < 4; ++t) {
            float h = fmaxf(fmaf(a2[t], A2, fmaf(a1[t], A1,
                              fmaf(a0[t], A0, A3))), 0.f);
            _Float16 hh = (_Float16)h;
            half2v h2; h2.x = hh; h2.y = hh;
            U4H8 f;
            #pragma unroll
            for (int j = 0; j < 4; ++j) f.p[j] = h2 * xf[t].p[j];
            // swapped operands: D = W'^T @ H^T = msg^T
            f32x4 a = (t==0) ? acc0 : (t==1) ? acc1 : (t==2) ? acc2 : acc3;
            a = __builtin_amdgcn_mfma_f32_16x16x32_f16(w.h, f.h, a, 0, 0, 0);
            if (t==0) acc0 = a; else if (t==1) acc1 = a;
            else if (t==2) acc2 = a; else acc3 = a;
        }
    }

    // lane (q,el) holds msg[edge el][o=q*4..q*4+3] -> one dwordx4 per tile
    #pragma unroll
    for (int t = 0; t < 4; ++t) {
        int row = __shfl(pAll, t*16 + el);
        f32x4 a = (t==0) ? acc0 : (t==1) ? acc1 : (t==2) ? acc2 : acc3;
        *(f32x4*)(msg_buf + (size_t)row * HID_C + q*4) = a;
    }
}

// 4 threads per node (thread = 4-channel group). Segment-sum msg rows
// [off[n], off[n+1]) as f32x4 -> mean -> + x@root (LDS) + bias -> ELU.
// (byte-identical to the R2 251.4us version)
__global__ __launch_bounds__(256) void node_gather_kernel(
    const float* __restrict__ xin, const float* __restrict__ msg_buf,
    const int* __restrict__ off,
    const float* __restrict__ root, const float* __restrict__ bias,
    float* __restrict__ xout, unsigned int* __restrict__ xh_out)
{
    __shared__ float root_s[IN_C * HID_C];
    if (threadIdx.x < 64)
        ((float4*)root_s)[threadIdx.x] = ((const float4*)root)[threadIdx.x];
    __syncthreads();

    int t = blockIdx.x * blockDim.x + threadIdx.x;
    int n = t >> 2;
    if (n >= N_NODES) return;
    int c0 = (t & 3) * 4;
    int lo = off[n], hi = off[n+1];
    float inv = 1.f / fmaxf((float)(hi - lo), 1.f);

    const f32x4* m4 = (const f32x4*)msg_buf;
    const int qi = c0 >> 2;
    f32x4 s0 = {0.f,0.f,0.f,0.f}, s1 = {0.f,0.f,0.f,0.f};
    int r = lo;
    for (; r + 2 <= hi; r += 2) {
        s0 += m4[(size_t)r*4 + qi];
        s1 += m4[(size_t)(r+1)*4 + qi];
    }
    if (r < hi) s0 += m4[(size_t)r*4 + qi];
    f32x4 s = s0 + s1;

    const float4 bv = *(const float4*)(bias + c0);
    f32x4 acc;
    acc.x = fmaf(s.x, inv, bv.x);
    acc.y = fmaf(s.y, inv, bv.y);
    acc.z = fmaf(s.z, inv, bv.z);
    acc.w = fmaf(s.w, inv, bv.w);

    const float4* x4 = (const float4*)(xin + (size_t)n * IN_C);
    #pragma unroll
    for (int j = 0; j < 4; ++j) {
        float4 xv = x4[j];
        #pragma unroll
        for (int k = 0; k < 4; ++k) {
            float xi = (k==0) ? xv.x : (k==1) ? xv.y : (k==2) ? xv.z : xv.w;
            const float4 rv = *(const float4*)(root_s + (j*4+k)*HID_C + c0);
            acc.x = fmaf(xi, rv.x, acc.x);
            acc.y = fmaf(xi, rv.y, acc.y);
            acc.z = fmaf(xi, rv.z, acc.z);
            acc.w = fmaf(xi, rv.w, acc.w);
        }
    }

    acc.x = acc.x > 0.f ? acc.x : (expf(acc.x) - 1.f);
    acc.y = acc.y > 0.f ? acc.y : (expf(acc.y) - 1.f);
    acc.z = acc.z > 0.f ? acc.z : (expf(acc.z) - 1.f);
    acc.w = acc.w > 0.f ? acc.w : (expf(acc.w) - 1.f);
    *(f32x4*)(xout + (size_t)n * HID_C + c0) = acc;

    if (xh_out) {
        HU h0, h1, h2, h3;
        h0.h = (_Float16)acc.x; h1.h = (_Float16)acc.y;
        h2.h = (_Float16)acc.z; h3.h = (_Float16)acc.w;
        uint2 pk;
        pk.x = (unsigned int)h0.u | ((unsigned int)h1.u << 16);
        pk.y = (unsigned int)h2.u | ((unsigned int)h3.u << 16);
        ((uint2*)xh_out)[n*4 + qi] = pk;
    }
}

// fused: global mean pool (batch sorted -> contiguous segments) + final linear
__global__ __launch_bounds__(64) void pool_final_kernel(
    const float* __restrict__ xin, const int* __restrict__ goff,
    const float* __restrict__ fcW, const float* __restrict__ fcb,
    float* __restrict__ out)
{
    __shared__ float part[4][HID_C];
    __shared__ float pooled[HID_C];
    int g = blockIdx.x;
    int t = threadIdx.x;
    int c = t & 15, sub = t >> 4;
    int lo = goff[g], hi = goff[g+1];
    float s = 0.f;
    for (int n = lo + sub; n < hi; n += 4)
        s += xin[(size_t)n*HID_C + c];
    part[sub][c] = s;
    __syncthreads();
    if (t < HID_C) {
        pooled[t] = (part[0][t] + part[1][t] + part[2][t] + part[3][t])
                    / fmaxf((float)(hi - lo), 1.f);
    }
    __syncthreads();
    if (t < OUT_C) {
        float acc = fcb[t];
        #pragma unroll
        for (int i = 0; i < HID_C; ++i)
            acc = fmaf(pooled[i], fcW[i*OUT_C+t], acc);
        out[g*OUT_C + t] = acc;
    }
}

// ---------------- launch ----------------

extern "C" void kernel_launch(void* const* d_in, const int* in_sizes, int n_in,
                              void* d_out, int out_size, void* d_ws, size_t ws_size,
                              hipStream_t stream)
{
    const float* x     = (const float*)d_in[0];
    const int*   ei    = (const int*)d_in[1];
    const float* eattr = (const float*)d_in[2];
    const int*   batch = (const int*)d_in[3];
    const float* W1a   = (const float*)d_in[4];
    const float* b1a   = (const float*)d_in[5];
    const float* g1    = (const float*)d_in[6];
    const float* bt1   = (const float*)d_in[7];
    const float* m1    = (const float*)d_in[8];
    const float* v1    = (const float*)d_in[9];
    const float* W1b   = (const float*)d_in[10];
    const float* b1b   = (const float*)d_in[11];
    const float* root1 = (const float*)d_in[12];
    const float* bias1 = (const float*)d_in[13];
    const float* W2a   = (const float*)d_in[14];
    const float* b2a   = (const float*)d_in[15];
    const float* g2    = (const float*)d_in[16];
    const float* bt2   = (const float*)d_in[17];
    const float* m2    = (const float*)d_in[18];
    const float* v2    = (const float*)d_in[19];
    const float* W2b   = (const float*)d_in[20];
    const float* b2b   = (const float*)d_in[21];
    const float* root2 = (const float*)d_in[22];
    const float* bias2 = (const float*)d_in[23];
    const float* fcW   = (const float*)d_in[24];
    const float* fcb   = (const float*)d_in[25];

    const int* src = ei;
    const int* dst = ei + N_EDGES;

    float* ws   = (float*)d_ws;
    float* MSG  = ws;                                   // 12,800,000 f
    float* X1   = ws + 12800000;                        //    800,000 f
    float* X2   = ws + 13600000;                        //    800,000 f
    int*   RANK = (int*)(ws + 14400000);                //    800,000 i
    int*   CNT  = (int*)(ws + 15200000);                //     50,000 i
    int*   TICK = (int*)(ws + 15250000);                //          1 i } memset
    int*   FLAG = (int*)(ws + 15250001);                //          1 i } w/ CNT
    int*   OFF  = (int*)(ws + 15250016);                //     50,001 i (+pad)
    int*   GOFF = (int*)(ws + 15300064);                //        501 i (+pad)
    unsigned int* WF1 = (unsigned int*)(ws + 15300576); //      3,328 u
    unsigned int* WF2 = (unsigned int*)(ws + 15303904); //      3,328 u
    float* AC1  = ws + 15307232;                        //        104 f (+pad)
    float* AC2  = ws + 15307344;                        //        104 f (+pad)
    int*   BSUM = (int*)(ws + 15307456);                //        196 i (+pad)
    int*   BPRE = (int*)(ws + 15307712);                //        196 i (+pad)
    float* EA4  = ws + 15308032;                        //  3,200,000 f (16B al.)
    unsigned int* XH0 = (unsigned int*)(ws + 18508032); //    400,000 u (f16 x)
    unsigned int* XH1 = (unsigned int*)(ws + 18908032); //    400,000 u (f16 X1)
    // total ~19,308,032 f = 77.2 MB

    // zero CNT + TICK + FLAG in one stream-ordered fill (50,016 ints)
    hipMemsetAsync(CNT, 0, 50016 * sizeof(int), stream);

    setup_kernel<<<9 + EDGE_NB, 256, 0, stream>>>(
        W1a, b1a, g1, bt1, m1, v1, W2a, b2a, g2, bt2, m2, v2,
        W1b, b1b, W2b, b2b, batch, x, eattr, dst,
        AC1, AC2, WF1, WF2, GOFF, CNT, RANK, (float4*)EA4, XH0);
    scan_kernel<<<SCAN_NB, 256, 0, stream>>>(CNT, BSUM, BPRE, OFF, TICK, FLAG);

    edge_mfma7_kernel<<<N_EDGES/256, 256, 0, stream>>>(
        (const unsigned short*)XH0, src, dst, RANK, OFF,
        (const float4*)EA4, AC1, WF1, MSG);
    node_gather_kernel<<<(N_NODES*4 + 255)/256, 256, 0, stream>>>(
        x, MSG, OFF, root1, bias1, X1, XH1);

    edge_mfma7_kernel<<<N_EDGES/256, 256, 0, stream>>>(
        (const unsigned short*)XH1, src, dst, RANK, OFF,
        (const float4*)EA4, AC2, WF2, MSG);
    node_gather_kernel<<<(N_NODES*4 + 255)/256, 256, 0, stream>>>(
        X1, MSG, OFF, root2, bias2, X2, (unsigned int*)nullptr);

    pool_final_kernel<<<N_GRAPHS, 64, 0, stream>>>(X2, GOFF, fcW, fcb, (float*)d_out);
}

// Round 8
// 252.844 us; speedup vs baseline: 2.8533x; 1.0075x over previous
//
#include <hip/hip_runtime.h>
#include <math.h>

#define N_NODES 50000
#define N_EDGES 800000
#define IN_C 16
#define HID_C 16
#define OUT_C 10
#define N_GRAPHS 500
#define EDGE_DIM 3
#define MLP_HID 25
#define BN_EPS 1e-5f

#define SCAN_NB ((N_NODES + 255) / 256)   // 196 blocks
#define EDGE_NB ((N_EDGES + 255) / 256)   // 3125 one-edge-per-thread blocks

typedef __attribute__((ext_vector_type(8))) _Float16 half8;
typedef __attribute__((ext_vector_type(2))) _Float16 half2v;
typedef __attribute__((ext_vector_type(4))) float f32x4;
union U4H8 { uint4 u; half8 h; half2v p[4]; };
union HU { _Float16 h; unsigned short u; };

// ---------------- setup: W-pack(f16) + BN-fold + goff + repack + rank -------
// One edge per thread in blocks 9.. (R7). Duration ~44us is overlap with the
// harness poison fill (parallelism-insensitive, VALU/BW idle) - not own cost.
__global__ __launch_bounds__(256) void setup_kernel(
    const float* __restrict__ W1a, const float* __restrict__ b1a,
    const float* __restrict__ g1, const float* __restrict__ bt1,
    const float* __restrict__ m1, const float* __restrict__ v1,
    const float* __restrict__ W2a, const float* __restrict__ b2a,
    const float* __restrict__ g2, const float* __restrict__ bt2,
    const float* __restrict__ m2, const float* __restrict__ v2,
    const float* __restrict__ W1b, const float* __restrict__ b1b,
    const float* __restrict__ W2b, const float* __restrict__ b2b,
    const int* __restrict__ batch,
    const float* __restrict__ xin, const float* __restrict__ eattr,
    const int* __restrict__ dst,
    float* __restrict__ AC1, float* __restrict__ AC2,
    unsigned int* __restrict__ WF1, unsigned int* __restrict__ WF2,
    int* __restrict__ goff, int* __restrict__ cnt, int* __restrict__ rank_out,
    float4* __restrict__ ea4, unsigned int* __restrict__ xh0)
{
    const int blk = blockIdx.x;
    const int tid = threadIdx.x;
    if (blk < 7) {
        int t = blk * 256 + tid;
        if (t >= 1664) return;
        const float *Wb, *bb; unsigned int *WH;
        int tl = t;
        if (t < 832) { Wb = W1b; bb = b1b; WH = WF1; }
        else { tl = t - 832; Wb = W2b; bb = b2b; WH = WF2; }
        int m = tl >> 6;
        int L = tl & 63;
        int q = L >> 4, o = L & 15;
        unsigned int hi[8];
        for (int j = 0; j < 8; ++j) {
            int kp = m*32 + q*8 + j;          // 0..415
            int k = kp >> 4, i = kp & 15;
            float w = (k < 25) ? Wb[k*256 + i*16 + o] : bb[i*16 + o];
            HU cv; cv.h = (_Float16)w;        // f16 RNE
            hi[j] = cv.u;
        }
        int base = (m*64 + L) * 4;
        for (int d = 0; d < 4; ++d)
            WH[base + d] = hi[2*d] | (hi[2*d+1] << 16);
        return;
    }
    if (blk == 7 || blk == 8) {
        if (blk == 7) {
            if (tid < 26) {
                int k = tid;
                if (k < 25) {
                    float sc = g1[k] / sqrtf(v1[k] + BN_EPS);
                    AC1[k*4+0] = sc * W1a[0*MLP_HID+k];
                    AC1[k*4+1] = sc * W1a[1*MLP_HID+k];
                    AC1[k*4+2] = sc * W1a[2*MLP_HID+k];
                    AC1[k*4+3] = sc * (b1a[k] - m1[k]) + bt1[k];
                } else {
                    AC1[100] = 0.f; AC1[101] = 0.f; AC1[102] = 0.f; AC1[103] = 1.f;
                }
            } else if (tid >= 32 && tid < 58) {
                int k = tid - 32;
                if (k < 25) {
                    float sc = g2[k] / sqrtf(v2[k] + BN_EPS);
                    AC2[k*4+0] = sc * W2a[0*MLP_HID+k];
                    AC2[k*4+1] = sc * W2a[1*MLP_HID+k];
                    AC2[k*4+2] = sc * W2a[2*MLP_HID+k];
                    AC2[k*4+3] = sc * (b2a[k] - m2[k]) + bt2[k];
                } else {
                    AC2[100] = 0.f; AC2[101] = 0.f; AC2[102] = 0.f; AC2[103] = 1.f;
                }
            }
        }
        int g = (blk - 7) * 256 + tid;
        if (g <= N_GRAPHS) {
            int lo = 0, hi = N_NODES;
            while (lo < hi) {
                int mid = (lo + hi) >> 1;
                if (batch[mid] < g) lo = mid + 1; else hi = mid;
            }
            goff[g] = lo;
        }
        return;
    }
    // one edge per thread: eattr repack + rank atomic (+x convert for half)
    const int e = (blk - 9) * 256 + tid;
    if (e < N_EDGES) {
        float4 a;
        a.x = eattr[e*3+0];
        a.y = eattr[e*3+1];
        a.z = eattr[e*3+2];
        a.w = 0.f;
        ea4[e] = a;
        rank_out[e] = atomicAdd(&cnt[dst[e]], 1);
    }
    if (e < 400000) {
        float2 v = ((const float2*)xin)[e];
        HU h0; h0.h = (_Float16)v.x;
        HU h1; h1.h = (_Float16)v.y;
        xh0[e] = (unsigned int)h0.u | ((unsigned int)h1.u << 16);
    }
}

// ---------------- CSR offsets: single-pass scan (verified R6/R7) -----------
__global__ __launch_bounds__(256) void scan_kernel(
    const int* __restrict__ cnt, int* __restrict__ bsum,
    int* __restrict__ bpre, int* __restrict__ off,
    int* __restrict__ ticket, int* __restrict__ flag)
{
    __shared__ int lds[256];
    __shared__ int sDone;
    int t = threadIdx.x;
    int idx = blockIdx.x * 256 + t;
    int v = (idx < N_NODES) ? cnt[idx] : 0;
    lds[t] = v;
    __syncthreads();
    for (int d = 1; d < 256; d <<= 1) {
        int u = (t >= d) ? lds[t - d] : 0;
        __syncthreads();
        lds[t] += u;
        __syncthreads();
    }
    const int myincl = lds[t];     // inclusive prefix within block
    const int btot   = lds[255];
    if (t == 0) {
        bsum[blockIdx.x] = btot;
        __threadfence();
        sDone = atomicAdd(ticket, 1);
    }
    __syncthreads();
    if (sDone == SCAN_NB - 1) {
        __threadfence();
        int b = (t < SCAN_NB) ? bsum[t] : 0;
        __syncthreads();
        lds[t] = b;
        __syncthreads();
        for (int d = 1; d < 256; d <<= 1) {
            int u = (t >= d) ? lds[t - d] : 0;
            __syncthreads();
            lds[t] += u;
            __syncthreads();
        }
        if (t < SCAN_NB) bpre[t] = (t > 0) ? lds[t - 1] : 0;
        if (t == 255) off[N_NODES] = lds[255];
        __threadfence();
        if (t == 0)
            __hip_atomic_store(flag, 1, __ATOMIC_RELEASE,
                               __HIP_MEMORY_SCOPE_AGENT);
    } else {
        if (t == 0) {
            while (__hip_atomic_load(flag, __ATOMIC_RELAXED,
                                     __HIP_MEMORY_SCOPE_AGENT) == 0)
                __builtin_amdgcn_s_sleep(2);
            __threadfence();
        }
        __syncthreads();
    }
    if (idx < N_NODES) off[idx] = bpre[blockIdx.x] + myincl - v;
}

// ---------------- hot path: f16 MFMA edge kernel, 4 tiles/wave --------------
// TRUE R2 body: PLAIN MSG store (R4's leftover nontemporal_store evicted the
// 51.2MB MSG stream from L3 and made node_gather re-fetch it from HBM --
// ~100MB avoidable HBM traffic per layer pair).
__global__ __launch_bounds__(256) void edge_mfma7_kernel(
    const unsigned short* __restrict__ xh,
    const int* __restrict__ src,
    const int* __restrict__ dst,
    const int* __restrict__ rank,
    const int* __restrict__ off,
    const float4* __restrict__ ea4,
    const float* __restrict__ AC,
    const unsigned int* __restrict__ WF,
    float* __restrict__ msg_buf)
{
    __shared__ uint4 wf_s[832];                         // 13312 B
    const int tid = threadIdx.x;
    #pragma unroll
    for (int it = 0; it < 4; ++it) {
        int gi = tid + it*256;
        if (gi < 832) wf_s[gi] = ((const uint4*)WF)[gi];
    }
    __syncthreads();

    const int wave = tid >> 6;
    const int lane = tid & 63;
    const int q    = lane >> 4;
    const int el   = lane & 15;
    const int i0   = (q & 1) * 8;
    const bool bsel = (q >> 1) != 0;
    const int E0   = (blockIdx.x * 4 + wave) * 64;

    // coalesced scalar plane: lane L <-> edge E0+L
    const int sAll = src[E0 + lane];
    const int dAll = dst[E0 + lane];
    const int rAll = rank[E0 + lane];
    const int pAll = off[dAll] + rAll;     // CSR slot of edge E0+lane

    // per-tile src via shuffle; eattr as one float4 per (t,el)
    int   sT[4];
    float a0[4], a1[4], a2[4];
    #pragma unroll
    for (int t = 0; t < 4; ++t) {
        sT[t] = __shfl(sAll, t*16 + el);
        float4 at = ea4[E0 + t*16 + el];
        a0[t] = at.x; a1[t] = at.y; a2[t] = at.z;
    }

    // x gather: one dwordx4 of pre-converted f16 per tile
    U4H8 xf[4];
    #pragma unroll
    for (int t = 0; t < 4; ++t)
        xf[t].u = *(const uint4*)(const void*)(xh + (size_t)sT[t]*16 + i0);

    f32x4 acc0 = {0.f,0.f,0.f,0.f}, acc1 = {0.f,0.f,0.f,0.f};
    f32x4 acc2 = {0.f,0.f,0.f,0.f}, acc3 = {0.f,0.f,0.f,0.f};
    #pragma unroll 1
    for (int m = 0; m < 13; ++m) {
        // wave-uniform s_load of AC rows 2m, 2m+1; per-lane parity select
        const float4 Ae = *(const float4*)(AC + m*8);
        const float4 Ao = *(const float4*)(AC + m*8 + 4);
        const float A0 = bsel ? Ao.x : Ae.x;
        const float A1 = bsel ? Ao.y : Ae.y;
        const float A2 = bsel ? Ao.z : Ae.z;
        const float A3 = bsel ? Ao.w : Ae.w;
        U4H8 w; w.u = wf_s[m*64 + lane];     // ds_read_b128 (LDS pipe)
        #pragma unroll
        for (int t = 0; t < 4; ++t) {
            float h = fmaxf(fmaf(a2[t], A2, fmaf(a1[t], A1,
                              fmaf(a0[t], A0, A3))), 0.f);
            _Float16 hh = (_Float16)h;
            half2v h2; h2.x = hh; h2.y = hh;
            U4H8 f;
            #pragma unroll
            for (int j = 0; j < 4; ++j) f.p[j] = h2 * xf[t].p[j];
            // swapped operands: D = W'^T @ H^T = msg^T
            f32x4 a = (t==0) ? acc0 : (t==1) ? acc1 : (t==2) ? acc2 : acc3;
            a = __builtin_amdgcn_mfma_f32_16x16x32_f16(w.h, f.h, a, 0, 0, 0);
            if (t==0) acc0 = a; else if (t==1) acc1 = a;
            else if (t==2) acc2 = a; else acc3 = a;
        }
    }

    // lane (q,el) holds msg[edge el][o=q*4..q*4+3] -> one dwordx4 per tile
    #pragma unroll
    for (int t = 0; t < 4; ++t) {
        int row = __shfl(pAll, t*16 + el);
        f32x4 a = (t==0) ? acc0 : (t==1) ? acc1 : (t==2) ? acc2 : acc3;
        *(f32x4*)(msg_buf + (size_t)row * HID_C + q*4) = a;
    }
}

// 16 threads per node: 4 channel-quarters (qi) x 4 edge-strides (h).
// R4 structure (verified bit-identical absmax) with PLAIN loads -- R4's
// regression was the bundled nontemporal hints, not this layout. 12500
// waves (12/SIMD) and 4x shorter serial loops vs 4-thr/node; a node's 16
// lanes read 256B contiguous per step (L3-resident MSG).
__global__ __launch_bounds__(256) void node_gather_kernel(
    const float* __restrict__ xin, const float* __restrict__ msg_buf,
    const int* __restrict__ off,
    const float* __restrict__ root, const float* __restrict__ bias,
    float* __restrict__ xout, unsigned int* __restrict__ xh_out)
{
    __shared__ float root_s[IN_C * HID_C];
    if (threadIdx.x < 64)
        ((float4*)root_s)[threadIdx.x] = ((const float4*)root)[threadIdx.x];
    __syncthreads();

    int t = blockIdx.x * blockDim.x + threadIdx.x;   // exactly N_NODES*16
    int n  = t >> 4;
    int sub = t & 15;
    int qi = sub & 3;
    int h  = sub >> 2;
    int lo = off[n], hi = off[n+1];
    float inv = 1.f / fmaxf((float)(hi - lo), 1.f);

    const f32x4* m4 = (const f32x4*)msg_buf;
    f32x4 s0 = {0.f,0.f,0.f,0.f}, s1 = {0.f,0.f,0.f,0.f};
    int r = lo + h;
    for (; r + 4 < hi; r += 8) {
        s0 += m4[(size_t)r*4 + qi];
        s1 += m4[(size_t)(r+4)*4 + qi];
    }
    if (r < hi) s0 += m4[(size_t)r*4 + qi];
    f32x4 p = s0 + s1;
    p.x *= inv; p.y *= inv; p.z *= inv; p.w *= inv;

    // partial x@root over input channels h*4 .. h*4+3
    const float4 xv = ((const float4*)(xin + (size_t)n * IN_C))[h];
    #pragma unroll
    for (int k = 0; k < 4; ++k) {
        float xi = (k==0) ? xv.x : (k==1) ? xv.y : (k==2) ? xv.z : xv.w;
        const float4 rv = *(const float4*)(root_s + (h*4+k)*HID_C + qi*4);
        p.x = fmaf(xi, rv.x, p.x);
        p.y = fmaf(xi, rv.y, p.y);
        p.z = fmaf(xi, rv.z, p.z);
        p.w = fmaf(xi, rv.w, p.w);
    }

    // fold the 4 h-strides (lanes ^4, ^8 stay inside the 16-lane node group)
    #pragma unroll
    for (int mask = 4; mask <= 8; mask <<= 1) {
        p.x += __shfl_xor(p.x, mask);
        p.y += __shfl_xor(p.y, mask);
        p.z += __shfl_xor(p.z, mask);
        p.w += __shfl_xor(p.w, mask);
    }

    if (h == 0) {
        const int c0 = qi * 4;
        const float4 bv = *(const float4*)(bias + c0);
        f32x4 acc;
        acc.x = p.x + bv.x;
        acc.y = p.y + bv.y;
        acc.z = p.z + bv.z;
        acc.w = p.w + bv.w;
        acc.x = acc.x > 0.f ? acc.x : (expf(acc.x) - 1.f);
        acc.y = acc.y > 0.f ? acc.y : (expf(acc.y) - 1.f);
        acc.z = acc.z > 0.f ? acc.z : (expf(acc.z) - 1.f);
        acc.w = acc.w > 0.f ? acc.w : (expf(acc.w) - 1.f);
        *(f32x4*)(xout + (size_t)n * HID_C + c0) = acc;

        if (xh_out) {
            HU h0, h1, h2, h3;
            h0.h = (_Float16)acc.x; h1.h = (_Float16)acc.y;
            h2.h = (_Float16)acc.z; h3.h = (_Float16)acc.w;
            uint2 pk;
            pk.x = (unsigned int)h0.u | ((unsigned int)h1.u << 16);
            pk.y = (unsigned int)h2.u | ((unsigned int)h3.u << 16);
            ((uint2*)xh_out)[n*4 + qi] = pk;
        }
    }
}

// fused: global mean pool (batch sorted -> contiguous segments) + final linear
__global__ __launch_bounds__(64) void pool_final_kernel(
    const float* __restrict__ xin, const int* __restrict__ goff,
    const float* __restrict__ fcW, const float* __restrict__ fcb,
    float* __restrict__ out)
{
    __shared__ float part[4][HID_C];
    __shared__ float pooled[HID_C];
    int g = blockIdx.x;
    int t = threadIdx.x;
    int c = t & 15, sub = t >> 4;
    int lo = goff[g], hi = goff[g+1];
    float s = 0.f;
    for (int n = lo + sub; n < hi; n += 4)
        s += xin[(size_t)n*HID_C + c];
    part[sub][c] = s;
    __syncthreads();
    if (t < HID_C) {
        pooled[t] = (part[0][t] + part[1][t] + part[2][t] + part[3][t])
                    / fmaxf((float)(hi - lo), 1.f);
    }
    __syncthreads();
    if (t < OUT_C) {
        float acc = fcb[t];
        #pragma unroll
        for (int i = 0; i < HID_C; ++i)
            acc = fmaf(pooled[i], fcW[i*OUT_C+t], acc);
        out[g*OUT_C + t] = acc;
    }
}

// ---------------- launch ----------------

extern "C" void kernel_launch(void* const* d_in, const int* in_sizes, int n_in,
                              void* d_out, int out_size, void* d_ws, size_t ws_size,
                              hipStream_t stream)
{
    const float* x     = (const float*)d_in[0];
    const int*   ei    = (const int*)d_in[1];
    const float* eattr = (const float*)d_in[2];
    const int*   batch = (const int*)d_in[3];
    const float* W1a   = (const float*)d_in[4];
    const float* b1a   = (const float*)d_in[5];
    const float* g1    = (const float*)d_in[6];
    const float* bt1   = (const float*)d_in[7];
    const float* m1    = (const float*)d_in[8];
    const float* v1    = (const float*)d_in[9];
    const float* W1b   = (const float*)d_in[10];
    const float* b1b   = (const float*)d_in[11];
    const float* root1 = (const float*)d_in[12];
    const float* bias1 = (const float*)d_in[13];
    const float* W2a   = (const float*)d_in[14];
    const float* b2a   = (const float*)d_in[15];
    const float* g2    = (const float*)d_in[16];
    const float* bt2   = (const float*)d_in[17];
    const float* m2    = (const float*)d_in[18];
    const float* v2    = (const float*)d_in[19];
    const float* W2b   = (const float*)d_in[20];
    const float* b2b   = (const float*)d_in[21];
    const float* root2 = (const float*)d_in[22];
    const float* bias2 = (const float*)d_in[23];
    const float* fcW   = (const float*)d_in[24];
    const float* fcb   = (const float*)d_in[25];

    const int* src = ei;
    const int* dst = ei + N_EDGES;

    float* ws   = (float*)d_ws;
    float* MSG  = ws;                                   // 12,800,000 f
    float* X1   = ws + 12800000;                        //    800,000 f
    float* X2   = ws + 13600000;                        //    800,000 f
    int*   RANK = (int*)(ws + 14400000);                //    800,000 i
    int*   CNT  = (int*)(ws + 15200000);                //     50,000 i
    int*   TICK = (int*)(ws + 15250000);                //          1 i } memset
    int*   FLAG = (int*)(ws + 15250001);                //          1 i } w/ CNT
    int*   OFF  = (int*)(ws + 15250016);                //     50,001 i (+pad)
    int*   GOFF = (int*)(ws + 15300064);                //        501 i (+pad)
    unsigned int* WF1 = (unsigned int*)(ws + 15300576); //      3,328 u
    unsigned int* WF2 = (unsigned int*)(ws + 15303904); //      3,328 u
    float* AC1  = ws + 15307232;                        //        104 f (+pad)
    float* AC2  = ws + 15307344;                        //        104 f (+pad)
    int*   BSUM = (int*)(ws + 15307456);                //        196 i (+pad)
    int*   BPRE = (int*)(ws + 15307712);                //        196 i (+pad)
    float* EA4  = ws + 15308032;                        //  3,200,000 f (16B al.)
    unsigned int* XH0 = (unsigned int*)(ws + 18508032); //    400,000 u (f16 x)
    unsigned int* XH1 = (unsigned int*)(ws + 18908032); //    400,000 u (f16 X1)
    // total ~19,308,032 f = 77.2 MB

    // zero CNT + TICK + FLAG in one stream-ordered fill (50,016 ints)
    hipMemsetAsync(CNT, 0, 50016 * sizeof(int), stream);

    setup_kernel<<<9 + EDGE_NB, 256, 0, stream>>>(
        W1a, b1a, g1, bt1, m1, v1, W2a, b2a, g2, bt2, m2, v2,
        W1b, b1b, W2b, b2b, batch, x, eattr, dst,
        AC1, AC2, WF1, WF2, GOFF, CNT, RANK, (float4*)EA4, XH0);
    scan_kernel<<<SCAN_NB, 256, 0, stream>>>(CNT, BSUM, BPRE, OFF, TICK, FLAG);

    edge_mfma7_kernel<<<N_EDGES/256, 256, 0, stream>>>(
        (const unsigned short*)XH0, src, dst, RANK, OFF,
        (const float4*)EA4, AC1, WF1, MSG);
    node_gather_kernel<<<(N_NODES*16)/256, 256, 0, stream>>>(
        x, MSG, OFF, root1, bias1, X1, XH1);

    edge_mfma7_kernel<<<N_EDGES/256, 256, 0, stream>>>(
        (const unsigned short*)XH1, src, dst, RANK, OFF,
        (const float4*)EA4, AC2, WF2, MSG);
    node_gather_kernel<<<(N_NODES*16)/256, 256, 0, stream>>>(
        X1, MSG, OFF, root2, bias2, X2, (unsigned int*)nullptr);

    pool_final_kernel<<<N_GRAPHS, 64, 0, stream>>>(X2, GOFF, fcW, fcb, (float*)d_out);
}